// Round 1
// baseline (368.833 us; speedup 1.0000x reference)
//
#include <hip/hip_runtime.h>
#include <hip/hip_bf16.h>

#define SEQ 4096
#define DIM 512
#define BQ 16
#define BK 128
#define NTHREADS 512
#define NITER (SEQ / BK)     // 32
#define NDCH (DIM / 32)      // 16 d-chunks of 32 for MFMA K
#define SCALE 0.044194173824159216f  // 1/sqrt(512)

typedef __attribute__((ext_vector_type(8))) short short8;
typedef __attribute__((ext_vector_type(4))) float f32x4;

// fp32 -> bf16 round-to-nearest-even
__device__ __forceinline__ short f2bf(float f) {
  union { float f; unsigned u; } c; c.f = f;
  unsigned u = c.u;
  return (short)((u + 0x7FFFu + ((u >> 16) & 1u)) >> 16);
}

__device__ __forceinline__ short8 pack8(float4 a, float4 b) {
  short8 r;
  r[0] = f2bf(a.x); r[1] = f2bf(a.y); r[2] = f2bf(a.z); r[3] = f2bf(a.w);
  r[4] = f2bf(b.x); r[5] = f2bf(b.y); r[6] = f2bf(b.z); r[7] = f2bf(b.w);
  return r;
}

__global__ __launch_bounds__(NTHREADS) void attn_fused(
    const float* __restrict__ q, const float* __restrict__ k,
    const float* __restrict__ v, float* __restrict__ out) {
  // LDS: score tile (fp32), P tile (bf16, XOR-swizzled), softmax state
  __shared__ float s_lds[BQ][BK];                      // 8 KB
  __shared__ __align__(16) unsigned short p_lds[BQ * BK];  // 4 KB
  __shared__ float m_st[BQ], l_st[BQ], osc_st[BQ];

  const int tid  = threadIdx.x;
  const int lane = tid & 63;
  const int w    = tid >> 6;   // wave 0..7
  const int lr   = lane & 15;  // row/col within 16 (MFMA frag)
  const int lg   = lane >> 4;  // lane group 0..3
  const int qb   = blockIdx.x * BQ;

  if (tid < BQ) { m_st[tid] = -INFINITY; l_st[tid] = 0.f; }

  // ---- hoist Q fragments: A-frag lane layout: row=lr, k = lg*8 + j ----
  short8 qf[NDCH];
  {
    const float* qp = q + (size_t)(qb + lr) * DIM + lg * 8;
#pragma unroll
    for (int c = 0; c < NDCH; ++c) {
      float4 a = *(const float4*)(qp + c * 32);
      float4 b = *(const float4*)(qp + c * 32 + 4);
      qf[c] = pack8(a, b);
    }
  }

  // O accumulator: wave owns cols [w*64, w*64+64), 4 col-tiles of 16
  f32x4 oacc[4] = {};

  __syncthreads();

  for (int it = 0; it < NITER; ++it) {
    const int kb = it * BK;

    // ---- QK^T: wave w computes score sub-tile for keys [kb+w*16, +16) ----
    {
      const float* kp = k + (size_t)(kb + w * 16 + lr) * DIM + lg * 8;
      f32x4 sacc = {};
#pragma unroll
      for (int c = 0; c < NDCH; ++c) {
        float4 a = *(const float4*)(kp + c * 32);
        float4 b = *(const float4*)(kp + c * 32 + 4);
        short8 kf = pack8(a, b);
        sacc = __builtin_amdgcn_mfma_f32_16x16x32_bf16(qf[c], kf, sacc, 0, 0, 0);
      }
      // C/D layout: col = lr (key), row = lg*4 + r
#pragma unroll
      for (int r = 0; r < 4; ++r)
        s_lds[lg * 4 + r][w * 16 + lr] = sacc[r] * SCALE;
    }
    __syncthreads();

    // ---- online softmax: 32 lanes per row, 4 keys per lane ----
    {
      const int srow = tid >> 5;
      const int sj   = tid & 31;
      float4 sv = *(const float4*)&s_lds[srow][sj * 4];
      float tmax = fmaxf(fmaxf(sv.x, sv.y), fmaxf(sv.z, sv.w));
#pragma unroll
      for (int msk = 16; msk >= 1; msk >>= 1)
        tmax = fmaxf(tmax, __shfl_xor(tmax, msk));
      float mold = m_st[srow];
      float mnew = fmaxf(mold, tmax);
      float p0 = __expf(sv.x - mnew), p1 = __expf(sv.y - mnew);
      float p2 = __expf(sv.z - mnew), p3 = __expf(sv.w - mnew);
      float psum = (p0 + p1) + (p2 + p3);
#pragma unroll
      for (int msk = 16; msk >= 1; msk >>= 1)
        psum += __shfl_xor(psum, msk);
      if (sj == 0) {
        float sc = __expf(mold - mnew);
        l_st[srow] = l_st[srow] * sc + psum;
        m_st[srow] = mnew;
        osc_st[srow] = sc;
      }
      // P -> LDS bf16, 8B chunk, XOR-swizzle byte ^= (row&7)<<4
      ushort4 pb;
      pb.x = (unsigned short)f2bf(p0); pb.y = (unsigned short)f2bf(p1);
      pb.z = (unsigned short)f2bf(p2); pb.w = (unsigned short)f2bf(p3);
      int lin = srow * (BK * 2) + sj * 8;
      int swz = lin ^ ((srow & 7) << 4);
      *(ushort4*)((char*)p_lds + swz) = pb;
    }
    __syncthreads();

    // ---- rescale O, then PV ----
    {
      float osc[4];
#pragma unroll
      for (int r = 0; r < 4; ++r) osc[r] = osc_st[lg * 4 + r];
#pragma unroll
      for (int ct = 0; ct < 4; ++ct)
#pragma unroll
        for (int r = 0; r < 4; ++r) oacc[ct][r] *= osc[r];

#pragma unroll
      for (int kc = 0; kc < 4; ++kc) {
        // A-frag = P rows lr, k = kc*32 + lg*8 + j  (swizzled ds_read_b128)
        int lin = lr * (BK * 2) + (kc * 32 + 8 * lg) * 2;
        int swz = lin ^ ((lr & 7) << 4);
        short8 pf = *(const short8*)((const char*)p_lds + swz);
        // B-frag = V[kb+kc*32+lg*8+j][w*64 + ct*16 + lr]  (strided global)
        const float* vp0 = v + (size_t)(kb + kc * 32 + 8 * lg) * DIM + w * 64 + lr;
#pragma unroll
        for (int ct = 0; ct < 4; ++ct) {
          const float* vp = vp0 + ct * 16;
          short8 vf;
#pragma unroll
          for (int jj = 0; jj < 8; ++jj) vf[jj] = f2bf(vp[(size_t)jj * DIM]);
          oacc[ct] = __builtin_amdgcn_mfma_f32_16x16x32_bf16(pf, vf, oacc[ct], 0, 0, 0);
        }
      }
    }
    __syncthreads();
  }

  // ---- epilogue: divide by l, store fp32 ----
  {
    float linv[4];
#pragma unroll
    for (int r = 0; r < 4; ++r) linv[r] = 1.f / l_st[lg * 4 + r];
#pragma unroll
    for (int ct = 0; ct < 4; ++ct)
#pragma unroll
      for (int r = 0; r < 4; ++r)
        out[(size_t)(qb + lg * 4 + r) * DIM + w * 64 + ct * 16 + lr] =
            oacc[ct][r] * linv[r];
  }
}

extern "C" void kernel_launch(void* const* d_in, const int* in_sizes, int n_in,
                              void* d_out, int out_size, void* d_ws, size_t ws_size,
                              hipStream_t stream) {
  (void)in_sizes; (void)n_in; (void)d_ws; (void)ws_size; (void)out_size;
  const float* q = (const float*)d_in[0];
  const float* k = (const float*)d_in[1];
  const float* v = (const float*)d_in[2];
  float* out = (float*)d_out;
  attn_fused<<<SEQ / BQ, NTHREADS, 0, stream>>>(q, k, v, out);
}

// Round 2
// 288.759 us; speedup vs baseline: 1.2773x; 1.2773x over previous
//
#include <hip/hip_runtime.h>
#include <hip/hip_bf16.h>

#define SEQ 4096
#define DIM 512
#define SCALE 0.044194173824159216f  // 1/sqrt(512)

#define SPLITS 4
#define BQ 64
#define KVBLK 64
#define KEYS_PER_SPLIT (SEQ / SPLITS)    // 1024
#define ITERS (KEYS_PER_SPLIT / KVBLK)   // 16

typedef __attribute__((ext_vector_type(8))) short short8;
typedef __attribute__((ext_vector_type(4))) float f32x4;

__device__ __forceinline__ short f2bf(float f) {
  union { float f; unsigned u; } c; c.f = f;
  unsigned u = c.u;
  return (short)((u + 0x7FFFu + ((u >> 16) & 1u)) >> 16);
}

__device__ __forceinline__ short8 pack8(float4 a, float4 b) {
  short8 r;
  r[0] = f2bf(a.x); r[1] = f2bf(a.y); r[2] = f2bf(a.z); r[3] = f2bf(a.w);
  r[4] = f2bf(b.x); r[5] = f2bf(b.y); r[6] = f2bf(b.z); r[7] = f2bf(b.w);
  return r;
}

// ---------- prep: fp32 -> bf16 row-major (for K) ----------
__global__ void cvt_bf16(const float* __restrict__ in, ushort* __restrict__ ob, int n8) {
  int i = blockIdx.x * blockDim.x + threadIdx.x;
  if (i >= n8) return;
  const float4* p = (const float4*)(in + (size_t)i * 8);
  short8 v = pack8(p[0], p[1]);
  *(short8*)(ob + (size_t)i * 8) = v;
}

// ---------- prep: fp32 V (S x D) -> bf16 V^T (D x S) ----------
__global__ void transpose_bf16(const float* __restrict__ v, ushort* __restrict__ vt) {
  __shared__ float t[64][65];
  const int bs = blockIdx.x % (SEQ / 64);
  const int bd = blockIdx.x / (SEQ / 64);
  const int s0 = bs * 64, d0 = bd * 64;
  const int tid = threadIdx.x;
#pragma unroll
  for (int k = 0; k < 16; ++k) {
    int idx = k * 256 + tid;
    int r = idx >> 6, c = idx & 63;
    t[r][c] = v[(size_t)(s0 + r) * DIM + d0 + c];
  }
  __syncthreads();
#pragma unroll
  for (int k = 0; k < 16; ++k) {
    int idx = k * 256 + tid;
    int dr = idx >> 6, sc = idx & 63;
    vt[(size_t)(d0 + dr) * SEQ + s0 + sc] = (ushort)f2bf(t[sc][dr]);
  }
}

// ---------- fused attention, split over key ranges ----------
__global__ __launch_bounds__(512, 2) void attn_split(
    const float* __restrict__ q, const ushort* __restrict__ kbf,
    const ushort* __restrict__ vt, float* __restrict__ opart,
    float* __restrict__ ml) {
  __shared__ float s_lds[BQ][68];                        // 17.4 KB
  __shared__ __align__(16) unsigned short p_lds[BQ * KVBLK];  // 8 KB, swizzled
  __shared__ float m_st[BQ], l_st[BQ], osc_st[BQ];

  const int tid  = threadIdx.x;
  const int lane = tid & 63;
  const int w    = tid >> 6;
  const int lr   = lane & 15;
  const int lg   = lane >> 4;
  const int sp   = blockIdx.x & (SPLITS - 1);
  const int qb   = blockIdx.x >> 2;
  const int rg   = w & 3;    // row-group (16 rows)
  const int g2   = w >> 2;   // QK: key-half; PV: col-half (256 cols)
  const int qrow0 = qb * BQ;

  if (tid < BQ) { m_st[tid] = -INFINITY; l_st[tid] = 0.f; }

  // Q fragments: rows rg*16+lr, 16 d-chunks
  short8 qf[16];
  {
    const float* qp = q + (size_t)(qrow0 + rg * 16 + lr) * DIM + lg * 8;
#pragma unroll
    for (int c = 0; c < 16; ++c)
      qf[c] = pack8(*(const float4*)(qp + c * 32), *(const float4*)(qp + c * 32 + 4));
  }
  f32x4 oacc[16] = {};
  __syncthreads();

  for (int it = 0; it < ITERS; ++it) {
    const int kb = sp * KEYS_PER_SPLIT + it * KVBLK;

    // ---- QK^T: wave (rg,g2) -> rows rg*16.. x keys g2*32..+32 ----
    {
      f32x4 s0 = {}, s1 = {};
      const ushort* kp = kbf + (size_t)(kb + g2 * 32 + lr) * DIM + lg * 8;
#pragma unroll
      for (int c = 0; c < 16; ++c) {
        short8 k0 = *(const short8*)(kp + c * 32);
        short8 k1 = *(const short8*)(kp + (size_t)16 * DIM + c * 32);
        s0 = __builtin_amdgcn_mfma_f32_16x16x32_bf16(qf[c], k0, s0, 0, 0, 0);
        s1 = __builtin_amdgcn_mfma_f32_16x16x32_bf16(qf[c], k1, s1, 0, 0, 0);
      }
#pragma unroll
      for (int r = 0; r < 4; ++r) {
        s_lds[rg * 16 + lg * 4 + r][g2 * 32 + lr]      = s0[r] * SCALE;
        s_lds[rg * 16 + lg * 4 + r][g2 * 32 + 16 + lr] = s1[r] * SCALE;
      }
    }
    __syncthreads();

    // ---- online softmax: 8 lanes per row ----
    {
      const int srow = tid >> 3;
      const int sj   = (tid & 7) * 8;
      float4 a = *(const float4*)&s_lds[srow][sj];
      float4 b = *(const float4*)&s_lds[srow][sj + 4];
      float tmax = fmaxf(fmaxf(fmaxf(a.x, a.y), fmaxf(a.z, a.w)),
                         fmaxf(fmaxf(b.x, b.y), fmaxf(b.z, b.w)));
#pragma unroll
      for (int m = 1; m <= 4; m <<= 1) tmax = fmaxf(tmax, __shfl_xor(tmax, m));
      float mold = m_st[srow];
      float mnew = fmaxf(mold, tmax);
      float p0 = __expf(a.x - mnew), p1 = __expf(a.y - mnew);
      float p2 = __expf(a.z - mnew), p3 = __expf(a.w - mnew);
      float p4 = __expf(b.x - mnew), p5 = __expf(b.y - mnew);
      float p6 = __expf(b.z - mnew), p7 = __expf(b.w - mnew);
      float ps = ((p0 + p1) + (p2 + p3)) + ((p4 + p5) + (p6 + p7));
#pragma unroll
      for (int m = 1; m <= 4; m <<= 1) ps += __shfl_xor(ps, m);
      if ((tid & 7) == 0) {
        float sc = __expf(mold - mnew);
        osc_st[srow] = sc;
        l_st[srow] = l_st[srow] * sc + ps;
        m_st[srow] = mnew;
      }
      short8 pb;
      pb[0] = f2bf(p0); pb[1] = f2bf(p1); pb[2] = f2bf(p2); pb[3] = f2bf(p3);
      pb[4] = f2bf(p4); pb[5] = f2bf(p5); pb[6] = f2bf(p6); pb[7] = f2bf(p7);
      int ba = srow * 128 + ((sj * 2) ^ ((srow & 7) << 4));
      *(short8*)((char*)p_lds + ba) = pb;
    }
    __syncthreads();

    // ---- rescale O, PV: wave (rg,g2) -> rows rg*16.. x cols g2*256..+256 ----
    {
      float osc[4];
#pragma unroll
      for (int r = 0; r < 4; ++r) osc[r] = osc_st[rg * 16 + lg * 4 + r];
#pragma unroll
      for (int ct = 0; ct < 16; ++ct)
#pragma unroll
        for (int r = 0; r < 4; ++r) oacc[ct][r] *= osc[r];

#pragma unroll
      for (int kc = 0; kc < 2; ++kc) {
        const int prow = rg * 16 + lr;
        int ba = prow * 128 + ((kc * 64 + lg * 16) ^ ((prow & 7) << 4));
        short8 pf = *(const short8*)((const char*)p_lds + ba);
        const ushort* vp = vt + (size_t)(g2 * 256 + lr) * SEQ + kb + kc * 32 + lg * 8;
#pragma unroll
        for (int ct = 0; ct < 16; ++ct) {
          short8 vf = *(const short8*)(vp + (size_t)ct * 16 * SEQ);
          oacc[ct] = __builtin_amdgcn_mfma_f32_16x16x32_bf16(pf, vf, oacc[ct], 0, 0, 0);
        }
      }
    }
    __syncthreads();
  }

  // ---- epilogue: unnormalized partial O + (m,l) ----
  {
    float* op = opart + ((size_t)sp * SEQ + qrow0 + rg * 16) * DIM + g2 * 256;
#pragma unroll
    for (int ct = 0; ct < 16; ++ct)
#pragma unroll
      for (int r = 0; r < 4; ++r)
        op[(size_t)(lg * 4 + r) * DIM + ct * 16 + lr] = oacc[ct][r];
    if (tid < BQ) {
      size_t base = ((size_t)sp * SEQ + qrow0 + tid) * 2;
      ml[base]     = m_st[tid];
      ml[base + 1] = l_st[tid];
    }
  }
}

// ---------- combine split partials ----------
__global__ void combine(const float* __restrict__ opart, const float* __restrict__ ml,
                        float* __restrict__ out) {
  int gid = blockIdx.x * 256 + threadIdx.x;
  int row = gid >> 7;
  int dv  = (gid & 127) * 4;
  float m[SPLITS], l[SPLITS], wgt[SPLITS];
  float M = -INFINITY;
#pragma unroll
  for (int i = 0; i < SPLITS; ++i) {
    m[i] = ml[((size_t)i * SEQ + row) * 2];
    l[i] = ml[((size_t)i * SEQ + row) * 2 + 1];
    M = fmaxf(M, m[i]);
  }
  float L = 0.f;
#pragma unroll
  for (int i = 0; i < SPLITS; ++i) { wgt[i] = __expf(m[i] - M); L += l[i] * wgt[i]; }
  float inv = 1.f / L;
  float4 acc = {0.f, 0.f, 0.f, 0.f};
#pragma unroll
  for (int i = 0; i < SPLITS; ++i) {
    float4 o = *(const float4*)(opart + ((size_t)i * SEQ + row) * DIM + dv);
    acc.x += o.x * wgt[i]; acc.y += o.y * wgt[i];
    acc.z += o.z * wgt[i]; acc.w += o.w * wgt[i];
  }
  acc.x *= inv; acc.y *= inv; acc.z *= inv; acc.w *= inv;
  *(float4*)(out + (size_t)row * DIM + dv) = acc;
}

// ---------- fallback (round-0 kernel) if ws too small ----------
__global__ __launch_bounds__(512) void attn_fused_fb(
    const float* __restrict__ q, const float* __restrict__ k,
    const float* __restrict__ v, float* __restrict__ out) {
  __shared__ float s_lds[16][128];
  __shared__ __align__(16) unsigned short p_lds[16 * 128];
  __shared__ float m_st[16], l_st[16], osc_st[16];
  const int tid = threadIdx.x, lane = tid & 63, w = tid >> 6;
  const int lr = lane & 15, lg = lane >> 4, qb = blockIdx.x * 16;
  if (tid < 16) { m_st[tid] = -INFINITY; l_st[tid] = 0.f; }
  short8 qf[16];
  {
    const float* qp = q + (size_t)(qb + lr) * DIM + lg * 8;
#pragma unroll
    for (int c = 0; c < 16; ++c)
      qf[c] = pack8(*(const float4*)(qp + c * 32), *(const float4*)(qp + c * 32 + 4));
  }
  f32x4 oacc[4] = {};
  __syncthreads();
  for (int it = 0; it < SEQ / 128; ++it) {
    const int kb = it * 128;
    {
      const float* kp = k + (size_t)(kb + w * 16 + lr) * DIM + lg * 8;
      f32x4 sacc = {};
#pragma unroll
      for (int c = 0; c < 16; ++c) {
        short8 kf = pack8(*(const float4*)(kp + c * 32), *(const float4*)(kp + c * 32 + 4));
        sacc = __builtin_amdgcn_mfma_f32_16x16x32_bf16(qf[c], kf, sacc, 0, 0, 0);
      }
#pragma unroll
      for (int r = 0; r < 4; ++r) s_lds[lg * 4 + r][w * 16 + lr] = sacc[r] * SCALE;
    }
    __syncthreads();
    {
      const int srow = tid >> 5, sj = tid & 31;
      float4 sv = *(const float4*)&s_lds[srow][sj * 4];
      float tmax = fmaxf(fmaxf(sv.x, sv.y), fmaxf(sv.z, sv.w));
#pragma unroll
      for (int m = 16; m >= 1; m >>= 1) tmax = fmaxf(tmax, __shfl_xor(tmax, m));
      float mold = m_st[srow], mnew = fmaxf(mold, tmax);
      float p0 = __expf(sv.x - mnew), p1 = __expf(sv.y - mnew);
      float p2 = __expf(sv.z - mnew), p3 = __expf(sv.w - mnew);
      float psum = (p0 + p1) + (p2 + p3);
#pragma unroll
      for (int m = 16; m >= 1; m >>= 1) psum += __shfl_xor(psum, m);
      if (sj == 0) {
        float sc = __expf(mold - mnew);
        l_st[srow] = l_st[srow] * sc + psum; m_st[srow] = mnew; osc_st[srow] = sc;
      }
      ushort4 pb;
      pb.x = (unsigned short)f2bf(p0); pb.y = (unsigned short)f2bf(p1);
      pb.z = (unsigned short)f2bf(p2); pb.w = (unsigned short)f2bf(p3);
      int lin = srow * 256 + sj * 8;
      *(ushort4*)((char*)p_lds + (lin ^ ((srow & 7) << 4))) = pb;
    }
    __syncthreads();
    {
      float osc[4];
#pragma unroll
      for (int r = 0; r < 4; ++r) osc[r] = osc_st[lg * 4 + r];
#pragma unroll
      for (int ct = 0; ct < 4; ++ct)
#pragma unroll
        for (int r = 0; r < 4; ++r) oacc[ct][r] *= osc[r];
#pragma unroll
      for (int kc = 0; kc < 4; ++kc) {
        int lin = lr * 256 + (kc * 32 + 8 * lg) * 2;
        short8 pf = *(const short8*)((const char*)p_lds + (lin ^ ((lr & 7) << 4)));
        const float* vp0 = v + (size_t)(kb + kc * 32 + 8 * lg) * DIM + w * 64 + lr;
#pragma unroll
        for (int ct = 0; ct < 4; ++ct) {
          const float* vp = vp0 + ct * 16;
          short8 vf;
#pragma unroll
          for (int jj = 0; jj < 8; ++jj) vf[jj] = f2bf(vp[(size_t)jj * DIM]);
          oacc[ct] = __builtin_amdgcn_mfma_f32_16x16x32_bf16(pf, vf, oacc[ct], 0, 0, 0);
        }
      }
    }
    __syncthreads();
  }
  {
    float linv[4];
#pragma unroll
    for (int r = 0; r < 4; ++r) linv[r] = 1.f / l_st[lg * 4 + r];
#pragma unroll
    for (int ct = 0; ct < 4; ++ct)
#pragma unroll
      for (int r = 0; r < 4; ++r)
        out[(size_t)(qb + lg * 4 + r) * DIM + w * 64 + ct * 16 + lr] =
            oacc[ct][r] * linv[r];
  }
}

extern "C" void kernel_launch(void* const* d_in, const int* in_sizes, int n_in,
                              void* d_out, int out_size, void* d_ws, size_t ws_size,
                              hipStream_t stream) {
  (void)in_sizes; (void)n_in; (void)out_size;
  const float* q = (const float*)d_in[0];
  const float* k = (const float*)d_in[1];
  const float* v = (const float*)d_in[2];
  float* out = (float*)d_out;

  const size_t kbf_elems = (size_t)SEQ * DIM;
  const size_t vt_elems  = (size_t)DIM * SEQ;
  const size_t op_elems  = (size_t)SPLITS * SEQ * DIM;
  const size_t ml_elems  = (size_t)SPLITS * SEQ * 2;
  const size_t need = kbf_elems * 2 + vt_elems * 2 + op_elems * 4 + ml_elems * 4;

  if (ws_size >= need) {
    ushort* kbf  = (ushort*)d_ws;
    ushort* vtb  = kbf + kbf_elems;
    float* opart = (float*)(vtb + vt_elems);
    float* ml    = opart + op_elems;

    cvt_bf16<<<(SEQ * DIM / 8 + 255) / 256, 256, 0, stream>>>(k, kbf, SEQ * DIM / 8);
    transpose_bf16<<<(SEQ / 64) * (DIM / 64), 256, 0, stream>>>(v, vtb);
    attn_split<<<(SEQ / BQ) * SPLITS, 512, 0, stream>>>(q, kbf, vtb, opart, ml);
    combine<<<(SEQ * DIM / 4) / 256, 256, 0, stream>>>(opart, ml, out);
  } else {
    attn_fused_fb<<<SEQ / 16, 512, 0, stream>>>(q, k, v, out);
  }
}

// Round 3
// 91.584 us; speedup vs baseline: 4.0273x; 3.1529x over previous
//
#include <hip/hip_runtime.h>
#include <hip/hip_bf16.h>

#define SEQ 4096
#define DIM 512
#define SCALE 0.044194173824159216f  // 1/sqrt(512)

#define SPLITS 4
#define BQ 64
#define KVBLK 64
#define KEYS_PER_SPLIT (SEQ / SPLITS)    // 1024
#define ITERS (KEYS_PER_SPLIT / KVBLK)   // 16

typedef __attribute__((ext_vector_type(8))) short short8;
typedef __attribute__((ext_vector_type(4))) float f32x4;

__device__ __forceinline__ short f2bf(float f) {
  union { float f; unsigned u; } c; c.f = f;
  unsigned u = c.u;
  return (short)((u + 0x7FFFu + ((u >> 16) & 1u)) >> 16);
}

__device__ __forceinline__ short8 pack8(float4 a, float4 b) {
  short8 r;
  r[0] = f2bf(a.x); r[1] = f2bf(a.y); r[2] = f2bf(a.z); r[3] = f2bf(a.w);
  r[4] = f2bf(b.x); r[5] = f2bf(b.y); r[6] = f2bf(b.z); r[7] = f2bf(b.w);
  return r;
}

// async global->LDS, 16B per lane, dest = uniform base + lane*16
__device__ __forceinline__ void gload16(const void* g, void* l) {
  __builtin_amdgcn_global_load_lds(
      (const __attribute__((address_space(1))) unsigned int*)g,
      (__attribute__((address_space(3))) unsigned int*)l, 16, 0, 0);
}

// ---------- prep: fp32 -> bf16 row-major (for K) ----------
__global__ void cvt_bf16(const float* __restrict__ in, ushort* __restrict__ ob, int n8) {
  int i = blockIdx.x * blockDim.x + threadIdx.x;
  if (i >= n8) return;
  const float4* p = (const float4*)(in + (size_t)i * 8);
  short8 v = pack8(p[0], p[1]);
  *(short8*)(ob + (size_t)i * 8) = v;
}

// ---------- prep: fp32 V (S x D) -> bf16 V^T (D x S) ----------
__global__ void transpose_bf16(const float* __restrict__ v, ushort* __restrict__ vt) {
  __shared__ float t[64][65];
  const int bs = blockIdx.x % (SEQ / 64);
  const int bd = blockIdx.x / (SEQ / 64);
  const int s0 = bs * 64, d0 = bd * 64;
  const int tid = threadIdx.x;
#pragma unroll
  for (int k = 0; k < 16; ++k) {
    int idx = k * 256 + tid;
    int r = idx >> 6, c = idx & 63;
    t[r][c] = v[(size_t)(s0 + r) * DIM + d0 + c];
  }
  __syncthreads();
#pragma unroll
  for (int k = 0; k < 16; ++k) {
    int idx = k * 256 + tid;
    int dr = idx >> 6, sc = idx & 63;
    vt[(size_t)(d0 + dr) * SEQ + s0 + sc] = (ushort)f2bf(t[sc][dr]);
  }
}

// ---------- fused attention: K/V LDS-staged, counted-vmcnt pipeline ----------
__global__ __launch_bounds__(512) void attn_split(
    const float* __restrict__ q, const ushort* __restrict__ kbf,
    const ushort* __restrict__ vt, float* __restrict__ opart,
    float* __restrict__ ml) {
  __shared__ __align__(16) ushort kt[KVBLK * DIM];    // 64 KB, chunk ^= row&31
  __shared__ __align__(16) ushort vtt[DIM * KVBLK];   // 64 KB, chunk ^= drow&7
  __shared__ float s_lds[BQ][68];                     // 17.4 KB
  __shared__ __align__(16) ushort p_lds[BQ * KVBLK];  // 8 KB, byte ^= (row&7)<<4
  __shared__ float m_st[BQ], l_st[BQ], osc_st[BQ];

  const int tid  = threadIdx.x;
  const int lane = tid & 63;
  const int w    = tid >> 6;
  const int lr   = lane & 15;
  const int lg   = lane >> 4;
  const int sp   = blockIdx.x & (SPLITS - 1);
  const int qb   = blockIdx.x >> 2;
  const int rg   = w & 3;    // row-group (16 rows)
  const int g2   = w >> 2;   // QK: key-half; PV: col-half
  const int qrow0 = qb * BQ;
  const int kbase = sp * KEYS_PER_SPLIT;

  if (tid < BQ) { m_st[tid] = -INFINITY; l_st[tid] = 0.f; }

  // Q fragments: rows rg*16+lr, 16 d-chunks
  short8 qf[16];
  {
    const float* qp = q + (size_t)(qrow0 + rg * 16 + lr) * DIM + lg * 8;
#pragma unroll
    for (int c = 0; c < 16; ++c)
      qf[c] = pack8(*(const float4*)(qp + c * 32), *(const float4*)(qp + c * 32 + 4));
  }
  f32x4 oacc[16] = {};

  // ---- staging: wave w covers its slice; per-lane pre-swizzled source ----
  // K rows: 1024B each; LDS[r][chunk] = K[kb+r][chunk ^ (r&31)]
  auto stageK = [&](int kb) {
#pragma unroll
    for (int i = 0; i < 8; ++i) {
      int r = w * 8 + i;
      const ushort* src = kbf + (size_t)(kb + r) * DIM + ((lane ^ (r & 31)) * 8);
      gload16(src, &kt[r * DIM]);
    }
  };
  // V^T rows: 128B each (64 keys); LDS[d][chunk] = vt[d][kb + (chunk^(d&7))*8..]
  auto stageV = [&](int kb) {
#pragma unroll
    for (int j = 0; j < 8; ++j) {
      int r0 = w * 64 + j * 8;
      int rr = r0 + (lane >> 3);
      int c  = lane & 7;
      const ushort* src = vt + (size_t)rr * SEQ + kb + ((c ^ (rr & 7)) * 8);
      gload16(src, &vtt[r0 * KVBLK]);
    }
  };

  stageK(kbase);  // K(0) in flight

  for (int it = 0; it < ITERS; ++it) {
    const int kb = kbase + it * KVBLK;

    stageV(kb);  // V(t) in flight; lands during QK/softmax
    asm volatile("s_waitcnt vmcnt(8)" ::: "memory");  // K(t) landed (V(t)=8 outstanding)
    __builtin_amdgcn_s_barrier();                     // bar-a

    // ---- QK^T from LDS: wave (rg,g2) -> rows rg*16.. x keys g2*32..+32 ----
    {
      f32x4 s0 = {}, s1 = {};
      const int r0 = g2 * 32 + lr;
      const int r1 = r0 + 16;
      const char* ktb = (const char*)kt;
#pragma unroll
      for (int c = 0; c < 16; ++c) {
        short8 k0 = *(const short8*)(ktb + r0 * 1024 + (((c * 4 + lg) ^ (r0 & 31)) * 16));
        short8 k1 = *(const short8*)(ktb + r1 * 1024 + (((c * 4 + lg) ^ (r1 & 31)) * 16));
        s0 = __builtin_amdgcn_mfma_f32_16x16x32_bf16(qf[c], k0, s0, 0, 0, 0);
        s1 = __builtin_amdgcn_mfma_f32_16x16x32_bf16(qf[c], k1, s1, 0, 0, 0);
      }
#pragma unroll
      for (int r = 0; r < 4; ++r) {
        s_lds[rg * 16 + lg * 4 + r][g2 * 32 + lr]      = s0[r] * SCALE;
        s_lds[rg * 16 + lg * 4 + r][g2 * 32 + 16 + lr] = s1[r] * SCALE;
      }
    }
    asm volatile("s_waitcnt lgkmcnt(0)" ::: "memory");  // scores visible
    __builtin_amdgcn_s_barrier();                       // bar-b

    // ---- online softmax: 8 lanes per row ----
    {
      const int srow = tid >> 3;
      const int sj   = (tid & 7) * 8;
      float4 a = *(const float4*)&s_lds[srow][sj];
      float4 b = *(const float4*)&s_lds[srow][sj + 4];
      float tmax = fmaxf(fmaxf(fmaxf(a.x, a.y), fmaxf(a.z, a.w)),
                         fmaxf(fmaxf(b.x, b.y), fmaxf(b.z, b.w)));
#pragma unroll
      for (int m = 1; m <= 4; m <<= 1) tmax = fmaxf(tmax, __shfl_xor(tmax, m));
      float mold = m_st[srow];
      float mnew = fmaxf(mold, tmax);
      float p0 = __expf(a.x - mnew), p1 = __expf(a.y - mnew);
      float p2 = __expf(a.z - mnew), p3 = __expf(a.w - mnew);
      float p4 = __expf(b.x - mnew), p5 = __expf(b.y - mnew);
      float p6 = __expf(b.z - mnew), p7 = __expf(b.w - mnew);
      float ps = ((p0 + p1) + (p2 + p3)) + ((p4 + p5) + (p6 + p7));
#pragma unroll
      for (int m = 1; m <= 4; m <<= 1) ps += __shfl_xor(ps, m);
      if ((tid & 7) == 0) {
        float sc = __expf(mold - mnew);
        osc_st[srow] = sc;
        l_st[srow] = l_st[srow] * sc + ps;
        m_st[srow] = mnew;
      }
      short8 pb;
      pb[0] = f2bf(p0); pb[1] = f2bf(p1); pb[2] = f2bf(p2); pb[3] = f2bf(p3);
      pb[4] = f2bf(p4); pb[5] = f2bf(p5); pb[6] = f2bf(p6); pb[7] = f2bf(p7);
      int ba = srow * 128 + ((sj * 2) ^ ((srow & 7) << 4));
      *(short8*)((char*)p_lds + ba) = pb;
    }

    if (it + 1 < ITERS) stageK(kb + KVBLK);  // K(t+1) in flight; lands during PV

    asm volatile("s_waitcnt vmcnt(8)" ::: "memory");    // V(t) landed (K(t+1)=8 out)
    asm volatile("s_waitcnt lgkmcnt(0)" ::: "memory");  // p_lds/osc visible
    __builtin_amdgcn_s_barrier();                       // bar-c

    // ---- rescale O, PV from LDS: wave -> rows rg*16.. x cols g2*256..+256 ----
    {
      float osc[4];
#pragma unroll
      for (int r = 0; r < 4; ++r) osc[r] = osc_st[rg * 16 + lg * 4 + r];
#pragma unroll
      for (int ct = 0; ct < 16; ++ct)
#pragma unroll
        for (int r = 0; r < 4; ++r) oacc[ct][r] *= osc[r];

      const char* vb = (const char*)vtt;
#pragma unroll
      for (int kc = 0; kc < 2; ++kc) {
        const int prow = rg * 16 + lr;
        int ba = prow * 128 + ((kc * 64 + lg * 16) ^ ((prow & 7) << 4));
        short8 pf = *(const short8*)((const char*)p_lds + ba);
#pragma unroll
        for (int ct = 0; ct < 16; ++ct) {
          int drow = g2 * 256 + ct * 16 + lr;
          short8 vf = *(const short8*)(vb + drow * 128 + (((kc * 4 + lg) ^ (drow & 7)) * 16));
          oacc[ct] = __builtin_amdgcn_mfma_f32_16x16x32_bf16(pf, vf, oacc[ct], 0, 0, 0);
        }
      }
    }
    asm volatile("s_waitcnt lgkmcnt(0)" ::: "memory");  // vtt reads complete
    __builtin_amdgcn_s_barrier();                       // bar-d: vtt free for V(t+1)
  }

  // ---- epilogue: unnormalized partial O + (m,l) ----
  {
    float* op = opart + ((size_t)sp * SEQ + qrow0 + rg * 16) * DIM + g2 * 256;
#pragma unroll
    for (int ct = 0; ct < 16; ++ct)
#pragma unroll
      for (int r = 0; r < 4; ++r)
        op[(size_t)(lg * 4 + r) * DIM + ct * 16 + lr] = oacc[ct][r];
    if (tid < BQ) {
      size_t base = ((size_t)sp * SEQ + qrow0 + tid) * 2;
      ml[base]     = m_st[tid];
      ml[base + 1] = l_st[tid];
    }
  }
}

// ---------- combine split partials ----------
__global__ void combine(const float* __restrict__ opart, const float* __restrict__ ml,
                        float* __restrict__ out) {
  int gid = blockIdx.x * 256 + threadIdx.x;
  int row = gid >> 7;
  int dv  = (gid & 127) * 4;
  float m[SPLITS], l[SPLITS], wgt[SPLITS];
  float M = -INFINITY;
#pragma unroll
  for (int i = 0; i < SPLITS; ++i) {
    m[i] = ml[((size_t)i * SEQ + row) * 2];
    l[i] = ml[((size_t)i * SEQ + row) * 2 + 1];
    M = fmaxf(M, m[i]);
  }
  float L = 0.f;
#pragma unroll
  for (int i = 0; i < SPLITS; ++i) { wgt[i] = __expf(m[i] - M); L += l[i] * wgt[i]; }
  float inv = 1.f / L;
  float4 acc = {0.f, 0.f, 0.f, 0.f};
#pragma unroll
  for (int i = 0; i < SPLITS; ++i) {
    float4 o = *(const float4*)(opart + ((size_t)i * SEQ + row) * DIM + dv);
    acc.x += o.x * wgt[i]; acc.y += o.y * wgt[i];
    acc.z += o.z * wgt[i]; acc.w += o.w * wgt[i];
  }
  acc.x *= inv; acc.y *= inv; acc.z *= inv; acc.w *= inv;
  *(float4*)(out + (size_t)row * DIM + dv) = acc;
}

// ---------- fallback if ws too small ----------
__global__ __launch_bounds__(512) void attn_fused_fb(
    const float* __restrict__ q, const float* __restrict__ k,
    const float* __restrict__ v, float* __restrict__ out) {
  __shared__ float s_lds[16][128];
  __shared__ __align__(16) unsigned short p_lds[16 * 128];
  __shared__ float m_st[16], l_st[16], osc_st[16];
  const int tid = threadIdx.x, lane = tid & 63, w = tid >> 6;
  const int lr = lane & 15, lg = lane >> 4, qb = blockIdx.x * 16;
  if (tid < 16) { m_st[tid] = -INFINITY; l_st[tid] = 0.f; }
  short8 qf[16];
  {
    const float* qp = q + (size_t)(qb + lr) * DIM + lg * 8;
#pragma unroll
    for (int c = 0; c < 16; ++c)
      qf[c] = pack8(*(const float4*)(qp + c * 32), *(const float4*)(qp + c * 32 + 4));
  }
  f32x4 oacc[4] = {};
  __syncthreads();
  for (int it = 0; it < SEQ / 128; ++it) {
    const int kb = it * 128;
    {
      const float* kp = k + (size_t)(kb + w * 16 + lr) * DIM + lg * 8;
      f32x4 sacc = {};
#pragma unroll
      for (int c = 0; c < 16; ++c) {
        short8 kf = pack8(*(const float4*)(kp + c * 32), *(const float4*)(kp + c * 32 + 4));
        sacc = __builtin_amdgcn_mfma_f32_16x16x32_bf16(qf[c], kf, sacc, 0, 0, 0);
      }
#pragma unroll
      for (int r = 0; r < 4; ++r) s_lds[lg * 4 + r][w * 16 + lr] = sacc[r] * SCALE;
    }
    __syncthreads();
    {
      const int srow = tid >> 5, sj = tid & 31;
      float4 sv = *(const float4*)&s_lds[srow][sj * 4];
      float tmax = fmaxf(fmaxf(sv.x, sv.y), fmaxf(sv.z, sv.w));
#pragma unroll
      for (int m = 16; m >= 1; m >>= 1) tmax = fmaxf(tmax, __shfl_xor(tmax, m));
      float mold = m_st[srow], mnew = fmaxf(mold, tmax);
      float p0 = __expf(sv.x - mnew), p1 = __expf(sv.y - mnew);
      float p2 = __expf(sv.z - mnew), p3 = __expf(sv.w - mnew);
      float psum = (p0 + p1) + (p2 + p3);
#pragma unroll
      for (int m = 16; m >= 1; m >>= 1) psum += __shfl_xor(psum, m);
      if (sj == 0) {
        float sc = __expf(mold - mnew);
        l_st[srow] = l_st[srow] * sc + psum; m_st[srow] = mnew; osc_st[srow] = sc;
      }
      ushort4 pb;
      pb.x = (unsigned short)f2bf(p0); pb.y = (unsigned short)f2bf(p1);
      pb.z = (unsigned short)f2bf(p2); pb.w = (unsigned short)f2bf(p3);
      int lin = srow * 256 + sj * 8;
      *(ushort4*)((char*)p_lds + (lin ^ ((srow & 7) << 4))) = pb;
    }
    __syncthreads();
    {
      float osc[4];
#pragma unroll
      for (int r = 0; r < 4; ++r) osc[r] = osc_st[lg * 4 + r];
#pragma unroll
      for (int ct = 0; ct < 4; ++ct)
#pragma unroll
        for (int r = 0; r < 4; ++r) oacc[ct][r] *= osc[r];
#pragma unroll
      for (int kc = 0; kc < 4; ++kc) {
        int lin = lr * 256 + (kc * 32 + 8 * lg) * 2;
        short8 pf = *(const short8*)((const char*)p_lds + (lin ^ ((lr & 7) << 4)));
        const float* vp0 = v + (size_t)(kb + kc * 32 + 8 * lg) * DIM + w * 64 + lr;
#pragma unroll
        for (int ct = 0; ct < 4; ++ct) {
          const float* vp = vp0 + ct * 16;
          short8 vf;
#pragma unroll
          for (int jj = 0; jj < 8; ++jj) vf[jj] = f2bf(vp[(size_t)jj * DIM]);
          oacc[ct] = __builtin_amdgcn_mfma_f32_16x16x32_bf16(pf, vf, oacc[ct], 0, 0, 0);
        }
      }
    }
    __syncthreads();
  }
  {
    float linv[4];
#pragma unroll
    for (int r = 0; r < 4; ++r) linv[r] = 1.f / l_st[lg * 4 + r];
#pragma unroll
    for (int ct = 0; ct < 4; ++ct)
#pragma unroll
      for (int r = 0; r < 4; ++r)
        out[(size_t)(qb + lg * 4 + r) * DIM + w * 64 + ct * 16 + lr] =
            oacc[ct][r] * linv[r];
  }
}

extern "C" void kernel_launch(void* const* d_in, const int* in_sizes, int n_in,
                              void* d_out, int out_size, void* d_ws, size_t ws_size,
                              hipStream_t stream) {
  (void)in_sizes; (void)n_in; (void)out_size;
  const float* q = (const float*)d_in[0];
  const float* k = (const float*)d_in[1];
  const float* v = (const float*)d_in[2];
  float* out = (float*)d_out;

  const size_t kbf_elems = (size_t)SEQ * DIM;
  const size_t vt_elems  = (size_t)DIM * SEQ;
  const size_t op_elems  = (size_t)SPLITS * SEQ * DIM;
  const size_t ml_elems  = (size_t)SPLITS * SEQ * 2;
  const size_t need = kbf_elems * 2 + vt_elems * 2 + op_elems * 4 + ml_elems * 4;

  if (ws_size >= need) {
    ushort* kbf  = (ushort*)d_ws;
    ushort* vtb  = kbf + kbf_elems;
    float* opart = (float*)(vtb + vt_elems);
    float* ml    = opart + op_elems;

    cvt_bf16<<<(SEQ * DIM / 8 + 255) / 256, 256, 0, stream>>>(k, kbf, SEQ * DIM / 8);
    transpose_bf16<<<(SEQ / 64) * (DIM / 64), 256, 0, stream>>>(v, vtb);
    attn_split<<<(SEQ / BQ) * SPLITS, 512, 0, stream>>>(q, kbf, vtb, opart, ml);
    combine<<<(SEQ * DIM / 4) / 256, 256, 0, stream>>>(opart, ml, out);
  } else {
    attn_fused_fb<<<SEQ / 16, 512, 0, stream>>>(q, k, v, out);
  }
}